// Round 22
// baseline (181.210 us; speedup 1.0000x reference)
//
#include <hip/hip_runtime.h>
#include <stdint.h>

// MultiHeadedAttentionSANM: B=8,T=1024,F=1024,H=16,Dk=64,KERNEL=11
// Pipeline (4 launches): cvt_all | GEMM1 q128<0> (qkv, V transposed in-epilogue -> vt) |
//   attn_fsmn fat kernel | GEMM2 q128<1> (out = acc + bias + fsb)
// Both GEMMs: 128x128 tile, 4 waves, BK=32, 3-buf counted-vmcnt, 48KB LDS -> 3 blocks/CU.
// ws layout (bytes): hsb[0,16M) wqkvb[16M,22M) woutb[22M,24M) q[24M,40M) k[40M,56M)
//                    vt[56M,72M) ctx[72M,88M)
// hsb/wqkvb dead after GEMM1: fsb (16MB @ +65536) reuses it.
// total ws needed = 92,274,688 bytes

typedef uint16_t u16;
typedef float f32x4 __attribute__((ext_vector_type(4)));
typedef __bf16 bf16x8 __attribute__((ext_vector_type(8)));
typedef __bf16 bf16x2 __attribute__((ext_vector_type(2)));
typedef u16 u16x8 __attribute__((ext_vector_type(8)));
typedef u16 u16x4 __attribute__((ext_vector_type(4)));
typedef short s16x4 __attribute__((ext_vector_type(4)));

__device__ __forceinline__ u16 f2bf(float f) {
    union { float f; uint32_t u; } c; c.f = f;
    uint32_t u = c.u;
    return (u16)((u + 0x7fffu + ((u >> 16) & 1u)) >> 16);
}
__device__ __forceinline__ float bf2f(u16 h) {
    union { uint32_t u; float f; } c; c.u = ((uint32_t)h) << 16;
    return c.f;
}
__device__ __forceinline__ uint32_t pack_bf16(float a, float b) {
    bf16x2 t; t[0] = (__bf16)a; t[1] = (__bf16)b;
    union { bf16x2 v; uint32_t u; } c; c.v = t; return c.u;
}

// ---------------- fused fp32 -> bf16 convert (hs | Wqkv | Wout) ----------------
__global__ __launch_bounds__(256) void cvt_all(const float* __restrict__ hs,
                                               const float* __restrict__ wqkv,
                                               const float* __restrict__ wout,
                                               u16* __restrict__ hsb,
                                               u16* __restrict__ wqkvb,
                                               u16* __restrict__ woutb) {
    int bid = blockIdx.x;
    const float* src; u16* dst; int ib;
    if (bid < 8192)       { src = hs;   dst = hsb;   ib = bid; }
    else if (bid < 11264) { src = wqkv; dst = wqkvb; ib = bid - 8192; }
    else                  { src = wout; dst = woutb; ib = bid - 11264; }
    int i = (ib * 256 + threadIdx.x) * 4;
    float4 v = *reinterpret_cast<const float4*>(src + i);
    ushort4 o;
    o.x = f2bf(v.x); o.y = f2bf(v.y); o.z = f2bf(v.z); o.w = f2bf(v.w);
    *reinterpret_cast<ushort4*>(dst + i) = o;
}

// ===== 128x128 bf16 GEMM, BK=32, 3-buf counted-vmcnt — 4 waves, 3 blocks/CU ===========
// MODE 0 (GEMM1): q(x0.125*log2e)/k natural [B,H,T,64]; V-tiles (n0>=2048) in-epilogue
//                 LDS transpose -> vt [B,H,64,T] coalesced (t fast axis).
// MODE 1 (GEMM2): out = acc + bias + bf2f(fsb) — write-only d_out.
template<int MODE>
__global__ __launch_bounds__(256, 4) void gemm128t(
    const u16* __restrict__ A, const u16* __restrict__ Bw, int M, int N, int K,
    int ntiles_n, const float* __restrict__ bias,
    u16* __restrict__ qo, u16* __restrict__ ko, u16* __restrict__ vo,
    const u16* __restrict__ fsb, float* __restrict__ out)
{
    __shared__ u16 lds[24576];     // 48 KB: 3 bufs x (A 4096 + B 4096 u16)
    const int t = threadIdx.x;
    const int lane = t & 63;
    const int wave = t >> 6;                   // 0..3
    const int wr = wave >> 1, wc = wave & 1;   // 2x2 wave grid
    const int lr = lane & 15, lq = lane >> 4;
    const int r3 = lane >> 2, c4 = lane & 3;
    const int cpx = gridDim.x >> 3;
    const int bid = (blockIdx.x & 7) * cpx + (blockIdx.x >> 3);
    const int m0 = (bid / ntiles_n) * 128;
    const int n0 = (bid % ntiles_n) * 128;
    const int NT = K >> 5;

    const u16* AgW = A  + (size_t)(m0 + wave * 16 + r3) * K + c4 * 8;
    const u16* BgW = Bw + (size_t)(n0 + wave * 16 + r3) * K + c4 * 8;

    auto stage = [&](int buf, int tile) {
        u16* dA = lds + buf * 8192 + wave * 512;
        u16* dB = lds + buf * 8192 + 4096 + wave * 512;
        __builtin_amdgcn_global_load_lds(
            (const __attribute__((address_space(1))) void*)(AgW + tile * 32),
            (__attribute__((address_space(3))) void*)dA, 16, 0, 0);
        __builtin_amdgcn_global_load_lds(
            (const __attribute__((address_space(1))) void*)(AgW + (size_t)64 * K + tile * 32),
            (__attribute__((address_space(3))) void*)(dA + 2048), 16, 0, 0);
        __builtin_amdgcn_global_load_lds(
            (const __attribute__((address_space(1))) void*)(BgW + tile * 32),
            (__attribute__((address_space(3))) void*)dB, 16, 0, 0);
        __builtin_amdgcn_global_load_lds(
            (const __attribute__((address_space(1))) void*)(BgW + (size_t)64 * K + tile * 32),
            (__attribute__((address_space(3))) void*)(dB + 2048), 16, 0, 0);
    };

    f32x4 acc[4][4];
#pragma unroll
    for (int i = 0; i < 4; ++i)
#pragma unroll
        for (int j = 0; j < 4; ++j) acc[i][j] = (f32x4){0.f, 0.f, 0.f, 0.f};

    stage(0, 0);
    stage(1, 1);
    asm volatile("s_waitcnt vmcnt(4)" ::: "memory");
    __builtin_amdgcn_s_barrier();

    for (int T = 0; T < NT; ++T) {
        const int bcur = T % 3;
        const u16* Ab = lds + bcur * 8192;
        const u16* Bb = Ab + 4096;
        bf16x8 a[4], bb[4];
#pragma unroll
        for (int mm = 0; mm < 4; ++mm)
            a[mm] = *reinterpret_cast<const bf16x8*>(Ab + (wr * 64 + mm * 16 + lr) * 32 + lq * 8);
#pragma unroll
        for (int nn = 0; nn < 4; ++nn)
            bb[nn] = *reinterpret_cast<const bf16x8*>(Bb + (wc * 64 + nn * 16 + lr) * 32 + lq * 8);
        if (T + 2 < NT) stage((T + 2) % 3, T + 2);
        __builtin_amdgcn_s_setprio(1);
#pragma unroll
        for (int mm = 0; mm < 4; ++mm)
#pragma unroll
            for (int nn = 0; nn < 4; ++nn)
                acc[mm][nn] = __builtin_amdgcn_mfma_f32_16x16x32_bf16(a[mm], bb[nn], acc[mm][nn], 0, 0, 0);
        __builtin_amdgcn_s_setprio(0);
        if (T + 2 < NT)      asm volatile("s_waitcnt vmcnt(4)" ::: "memory");
        else if (T + 1 < NT) asm volatile("s_waitcnt vmcnt(0)" ::: "memory");
        if (T + 1 < NT) __builtin_amdgcn_s_barrier();
    }

    // ---------------- epilogue (D layout: col=lane&15, row=(lane>>4)*4+reg) ------------
    if (MODE == 0 && n0 >= 2048) {
        // V tile: per-wave LDS transpose patch, then coalesced vt stores (t fast axis).
        __syncthreads();                         // staging bufs done being read
        u16* patch = lds + wave * 4608;          // [64 col][72 row] u16 = 9216 B/wave
#pragma unroll
        for (int m = 0; m < 4; ++m)
#pragma unroll
            for (int n = 0; n < 4; ++n) {
                int c = n * 16 + lr;
                int rrl = m * 16 + lq * 4;
#pragma unroll
                for (int r = 0; r < 4; ++r)
                    patch[c * 72 + rrl + r] = f2bf(acc[m][n][r]);
            }
        const int col0 = n0 + wc * 64;
        const int row0 = m0 + wr * 64;
#pragma unroll
        for (int p = 0; p < 8; ++p) {
            int c = p * 8 + (lane >> 3);
            int tch = (lane & 7) * 8;
            u16x8 v = *reinterpret_cast<const u16x8*>(patch + c * 72 + tch);
            int col = col0 + c;
            int cc = col & 1023;
            int h = cc >> 6, d = cc & 63;
            int rg = row0 + tch;
            int b = rg >> 10, tt = rg & 1023;
            *reinterpret_cast<u16x8*>(vo + (((size_t)(b * 16 + h)) << 16) +
                                      (size_t)d * 1024 + tt) = v;
        }
    } else {
#pragma unroll
        for (int m = 0; m < 4; ++m) {
            int row = m0 + wr * 64 + m * 16 + lq * 4;
#pragma unroll
            for (int n = 0; n < 4; ++n) {
                int col = n0 + wc * 64 + n * 16 + lr;
                float bv = bias[col];
#pragma unroll
                for (int r = 0; r < 4; ++r) {
                    float val = acc[m][n][r] + bv;
                    int rr = row + r;
                    if (MODE == 0) {
                        int part = col >> 10;
                        int cc = col & 1023;
                        int h = cc >> 6, d = cc & 63;
                        int b = rr >> 10, tt = rr & 1023;
                        size_t bh = (size_t)(b * 16 + h);
                        u16* dst = (part == 0) ? qo : ko;
                        dst[((bh << 10) + tt) * 64 + d] = f2bf(part == 0 ? val * 0.18033688011f : val);
                    } else {
                        size_t o = (size_t)rr * N + col;
                        out[o] = val + bf2f(fsb[o]);
                    }
                }
            }
        }
    }
}

// ========== FAT kernel: blocks <1024 = attn v12; blocks >=1024 = fsmn (bf16 LDS) =======
__global__ __launch_bounds__(256) void attn_fsmn(const u16* __restrict__ qg,
                                                 const u16* __restrict__ kg,
                                                 const u16* __restrict__ vtg,
                                                 const int* __restrict__ mask,
                                                 const float* __restrict__ fk,
                                                 u16* __restrict__ ctx,
                                                 u16* __restrict__ fsb)
{
    __shared__ u16 smem[16384];   // 32 KB overlay
    if (blockIdx.x < 1024) {
        // ---------------- attention v12 body ----------------
        u16* K_sb = smem;          // [2][4096] u16
        u16* V_sb = smem + 8192;   // [2][4096] u16
        const int t = threadIdx.x;
        const int lane = t & 63;
        const int w = t >> 6;                 // 0..3
        const int lr = lane & 15, lq = lane >> 4;
        const int bh = blockIdx.x & 127;
        const int qc = blockIdx.x >> 7;       // 0..7
        const int b = bh >> 4, h = bh & 15;
        const size_t base = (size_t)bh << 16;
        const u16* kb = kg + base;            // [1024 key][64 d]
        const u16* vb = vtg + base;           // [64 d][1024 key]
        const int* mrow = mask + (b << 10);
        const int q0 = qc * 128 + w * 32;

        bf16x8 qf[2][2];
#pragma unroll
        for (int qt = 0; qt < 2; ++qt)
#pragma unroll
            for (int kk = 0; kk < 2; ++kk)
                qf[qt][kk] = *reinterpret_cast<const bf16x8*>(
                    qg + base + (size_t)(q0 + qt * 16 + lr) * 64 + kk * 32 + lq * 8);

        f32x4 oacc[2][4];
        f32x4 oacc_l[2];
#pragma unroll
        for (int qt = 0; qt < 2; ++qt) {
            oacc_l[qt] = (f32x4){0.f, 0.f, 0.f, 0.f};
#pragma unroll
            for (int dt = 0; dt < 4; ++dt) oacc[qt][dt] = (f32x4){0.f, 0.f, 0.f, 0.f};
        }

        s16x4 ones_f;
#pragma unroll
        for (int j = 0; j < 4; ++j) ones_f[j] = (short)0x3F80;

        auto stage = [&](int bufi, int tile) {
            const int k0s = tile * 64;
#pragma unroll
            for (int rd = 0; rd < 2; ++rd) {
                int ch = rd * 256 + w * 64 + lane;
                int row = ch >> 3, c7 = ch & 7;
                int sc = (c7 ^ (row & 7)) * 8;
                const u16* srcK = kb + (size_t)(k0s + row) * 64 + sc;
                const u16* srcV = vb + (size_t)row * 1024 + k0s + sc;
                u16* dK = K_sb + bufi * 4096 + (size_t)(rd * 256 + w * 64) * 8;
                u16* dV = V_sb + bufi * 4096 + (size_t)(rd * 256 + w * 64) * 8;
                __builtin_amdgcn_global_load_lds(
                    (const __attribute__((address_space(1))) void*)srcK,
                    (__attribute__((address_space(3))) void*)dK, 16, 0, 0);
                __builtin_amdgcn_global_load_lds(
                    (const __attribute__((address_space(1))) void*)srcV,
                    (__attribute__((address_space(3))) void*)dV, 16, 0, 0);
            }
        };

        stage(0, 0);
        asm volatile("s_waitcnt vmcnt(0)");
        __syncthreads();

        for (int it = 0; it < 16; ++it) {
            const u16* Kb = K_sb + (it & 1) * 4096;
            const u16* Vb = V_sb + (it & 1) * 4096;
            if (it < 15) stage((it + 1) & 1, it + 1);

            bf16x8 kf[4][2];
#pragma unroll
            for (int kt = 0; kt < 4; ++kt) {
                int row = kt * 16 + lr;
#pragma unroll
                for (int kk = 0; kk < 2; ++kk) {
                    int g = (kk * 4 + lq) ^ (row & 7);
                    kf[kt][kk] = *reinterpret_cast<const bf16x8*>(Kb + row * 64 + g * 8);
                }
            }

            int mv = mrow[it * 64 + lane];
            unsigned long long bal = __ballot(mv != 0);
            uint32_t mw0 = (uint32_t)bal, mw1 = (uint32_t)(bal >> 32);
            uint32_t mb_[4];
            mb_[0] = mw0 >> (lq * 4);
            mb_[1] = mw0 >> (16 + lq * 4);
            mb_[2] = mw1 >> (lq * 4);
            mb_[3] = mw1 >> (16 + lq * 4);
            f32x4 ma[4];
#pragma unroll
            for (int kt = 0; kt < 4; ++kt)
#pragma unroll
                for (int r = 0; r < 4; ++r)
                    ma[kt][r] = (mb_[kt] & (1u << r)) ? 0.f : -3e38f;

            s16x4 vf[4][4];
#pragma unroll
            for (int ks = 0; ks < 4; ++ks)
#pragma unroll
                for (int dt = 0; dt < 4; ++dt) {
                    int row = dt * 16 + lr;
                    int g = (ks * 2 + (lq >> 1)) ^ (row & 7);
                    vf[ks][dt] = *reinterpret_cast<const s16x4*>(Vb + row * 64 + g * 8 + (lq & 1) * 4);
                }

#pragma unroll
            for (int qt = 0; qt < 2; ++qt) {
                f32x4 s[4];
                __builtin_amdgcn_s_setprio(1);
#pragma unroll
                for (int kt = 0; kt < 4; ++kt) {
                    s[kt] = __builtin_amdgcn_mfma_f32_16x16x32_bf16(kf[kt][0], qf[qt][0], ma[kt], 0, 0, 0);
                    s[kt] = __builtin_amdgcn_mfma_f32_16x16x32_bf16(kf[kt][1], qf[qt][1], s[kt], 0, 0, 0);
                }
                __builtin_amdgcn_s_setprio(0);

                union { uint32_t u[2]; s16x4 v; } pa[4];
#pragma unroll
                for (int kt = 0; kt < 4; ++kt) {
                    float p0 = __builtin_amdgcn_exp2f(s[kt][0]);
                    float p1 = __builtin_amdgcn_exp2f(s[kt][1]);
                    float p2 = __builtin_amdgcn_exp2f(s[kt][2]);
                    float p3 = __builtin_amdgcn_exp2f(s[kt][3]);
                    pa[kt].u[0] = pack_bf16(p0, p1);
                    pa[kt].u[1] = pack_bf16(p2, p3);
                }

                __builtin_amdgcn_s_setprio(1);
#pragma unroll
                for (int dt = 0; dt < 4; ++dt) {
                    f32x4 o = oacc[qt][dt];
#pragma unroll
                    for (int kt = 0; kt < 4; ++kt)
                        o = __builtin_amdgcn_mfma_f32_16x16x16bf16_1k(vf[kt][dt], pa[kt].v, o, 0, 0, 0);
                    oacc[qt][dt] = o;
                }
#pragma unroll
                for (int kt = 0; kt < 4; ++kt)
                    oacc_l[qt] = __builtin_amdgcn_mfma_f32_16x16x16bf16_1k(ones_f, pa[kt].v, oacc_l[qt], 0, 0, 0);
                __builtin_amdgcn_s_setprio(0);
            }

            if (it < 15) {
                asm volatile("s_waitcnt vmcnt(0)" ::: "memory");
                __syncthreads();
            }
        }

#pragma unroll
        for (int qt = 0; qt < 2; ++qt) {
            float li = 1.f / oacc_l[qt][0];
            int trow = q0 + qt * 16 + lr;
            u16* crow = ctx + ((size_t)(b << 10) + trow) * 1024 + h * 64;
#pragma unroll
            for (int dt = 0; dt < 4; ++dt) {
                f32x4 o = oacc[qt][dt];
                u16x4 pkv;
                pkv[0] = f2bf(o[0] * li); pkv[1] = f2bf(o[1] * li);
                pkv[2] = f2bf(o[2] * li); pkv[3] = f2bf(o[3] * li);
                *reinterpret_cast<u16x4*>(crow + dt * 16 + lq * 4) = pkv;
            }
        }
    } else {
        // ---------------- FSMN body (bf16 LDS overlay, 19.4 KB) ----------------
        u16* vsu = smem;                                 // [64][147] u16 (premasked V)
        float* ms = (float*)(smem + 9408);               // [144] f32
        const int fb = blockIdx.x - 1024;
        const int tid = threadIdx.x;
        const int tc = fb & 7;
        const int bh = fb >> 3;
        const int b = bh >> 4, h = bh & 15;
        const int t0 = tc * 128;
        const u16* vrow = vtg + ((size_t)bh << 16);
        const int* mrow = mask + (b << 10);

        if (tid < 144) {
            int tt = t0 - 8 + tid;
            ms[tid] = (tt >= 0 && tt < 1024) ? (float)mrow[tt] : 0.f;
        }
        const int sd = tid >> 2;
        const int ci0 = tid & 3;
#pragma unroll
        for (int it = 0; it < 5; ++it) {
            int ci = ci0 + it * 4;
            if (ci < 18) {
                int tbase = t0 - 8 + ci * 8;
                if (tbase >= 0 && tbase < 1024) {
                    u16x8 v8 = *reinterpret_cast<const u16x8*>(vrow + (size_t)sd * 1024 + tbase);
#pragma unroll
                    for (int j = 0; j < 8; ++j)
                        vsu[sd * 147 + ci * 8 + j] = mrow[tbase + j] ? (u16)v8[j] : (u16)0;
                } else {
#pragma unroll
                    for (int j = 0; j < 8; ++j) vsu[sd * 147 + ci * 8 + j] = 0;
                }
            }
        }
        __syncthreads();

        const int dd = tid & 63;
        const int tg = tid >> 6;
        const int c = h * 64 + dd;
        float kc[11];
#pragma unroll
        for (int j = 0; j < 11; ++j) kc[j] = fk[c * 11 + j];

        const int tl0 = tg * 32;
        float w[11];
#pragma unroll
        for (int j = 0; j < 11; ++j) w[j] = bf2f(vsu[dd * 147 + 3 + tl0 + j]);
        u16* orow = fsb + ((size_t)(b * 1024 + t0 + tl0)) * 1024 + c;
#pragma unroll 4
        for (int s = 0; s < 32; ++s) {
            float acc = 0.f;
#pragma unroll
            for (int j = 0; j < 11; ++j) acc += kc[j] * w[j];
            float mf = ms[8 + tl0 + s];
            orow[(size_t)s * 1024] = f2bf((acc + w[5]) * mf);
#pragma unroll
            for (int j = 0; j < 10; ++j) w[j] = w[j + 1];
            w[10] = bf2f(vsu[dd * 147 + 3 + tl0 + s + 11]);
        }
    }
}

extern "C" void kernel_launch(void* const* d_in, const int* in_sizes, int n_in,
                              void* d_out, int out_size, void* d_ws, size_t ws_size,
                              hipStream_t stream)
{
    (void)in_sizes; (void)n_in; (void)out_size; (void)ws_size;
    const float* hs   = (const float*)d_in[0];
    const int*   mask = (const int*)d_in[1];
    const float* Wqkv = (const float*)d_in[2];
    const float* bqkv = (const float*)d_in[3];
    const float* Wout = (const float*)d_in[4];
    const float* bout = (const float*)d_in[5];
    const float* fk   = (const float*)d_in[6];
    float* out = (float*)d_out;

    char* ws = (char*)d_ws;
    u16* hsb   = (u16*)(ws);
    u16* wqkvb = (u16*)(ws + 16777216);
    u16* woutb = (u16*)(ws + 23068672);
    u16* qb    = (u16*)(ws + 25165824);      // [B,H,T,64]
    u16* kb    = (u16*)(ws + 41943040);      // [B,H,T,64]
    u16* vtb   = (u16*)(ws + 58720256);      // [B,H,64,T]
    u16* ctxb  = (u16*)(ws + 75497472);      // [B,T,1024]
    u16* fsb   = (u16*)(ws + 65536);         // 16MB bf16 fsmn memory (hsb+wqkvb region,
                                             //  written AFTER gemm1)

    cvt_all<<<12288, 256, 0, stream>>>(hs, Wqkv, Wout, hsb, wqkvb, woutb);

    gemm128t<0><<<64 * 24, 256, 0, stream>>>(hsb, wqkvb, 8192, 3072, 1024, 24,
                                             bqkv, qb, kb, vtb, nullptr, nullptr);
    attn_fsmn<<<2048, 256, 0, stream>>>(qb, kb, vtb, mask, fk, ctxb, fsb);
    gemm128t<1><<<64 * 8, 256, 0, stream>>>(ctxb, woutb, 8192, 1024, 1024, 8,
                                            bout, nullptr, nullptr, nullptr, fsb, out);
}

// Round 23
// 171.479 us; speedup vs baseline: 1.0568x; 1.0568x over previous
//
#include <hip/hip_runtime.h>
#include <stdint.h>

// MultiHeadedAttentionSANM: B=8,T=1024,F=1024,H=16,Dk=64,KERNEL=11
// Pipeline (4 launches): cvt_all | GEMM1 qkv bk32 (V transposed in-epilogue -> vt) |
//   attn_fsmn fat kernel (blocks<1024: attn v12; >=1024: fsmn bf16-LDS -> fsb) |
//   GEMM2 sq128 (out = acc + bias + fsb)
// ws layout (bytes): hsb[0,16M) wqkvb[16M,22M) woutb[22M,24M) q[24M,40M) k[40M,56M)
//                    vt[56M,72M) ctx[72M,88M)
// hsb/wqkvb dead after GEMM1: fsb (16MB @ +65536) reuses it.
// total ws needed = 92,274,688 bytes
// [r23 = exact revert to the r21 best state, 172.0 us: r22's 128x128 gemm1 halved
//  A-panel reuse (N=3072 -> 24 n-tiles) and regressed +9 us.]

typedef uint16_t u16;
typedef float f32x4 __attribute__((ext_vector_type(4)));
typedef __bf16 bf16x8 __attribute__((ext_vector_type(8)));
typedef __bf16 bf16x2 __attribute__((ext_vector_type(2)));
typedef u16 u16x8 __attribute__((ext_vector_type(8)));
typedef u16 u16x4 __attribute__((ext_vector_type(4)));
typedef short s16x4 __attribute__((ext_vector_type(4)));

__device__ __forceinline__ u16 f2bf(float f) {
    union { float f; uint32_t u; } c; c.f = f;
    uint32_t u = c.u;
    return (u16)((u + 0x7fffu + ((u >> 16) & 1u)) >> 16);
}
__device__ __forceinline__ float bf2f(u16 h) {
    union { uint32_t u; float f; } c; c.u = ((uint32_t)h) << 16;
    return c.f;
}
__device__ __forceinline__ uint32_t pack_bf16(float a, float b) {
    bf16x2 t; t[0] = (__bf16)a; t[1] = (__bf16)b;
    union { bf16x2 v; uint32_t u; } c; c.v = t; return c.u;
}

// ---------------- fused fp32 -> bf16 convert (hs | Wqkv | Wout) ----------------
__global__ __launch_bounds__(256) void cvt_all(const float* __restrict__ hs,
                                               const float* __restrict__ wqkv,
                                               const float* __restrict__ wout,
                                               u16* __restrict__ hsb,
                                               u16* __restrict__ wqkvb,
                                               u16* __restrict__ woutb) {
    int bid = blockIdx.x;
    const float* src; u16* dst; int ib;
    if (bid < 8192)       { src = hs;   dst = hsb;   ib = bid; }
    else if (bid < 11264) { src = wqkv; dst = wqkvb; ib = bid - 8192; }
    else                  { src = wout; dst = woutb; ib = bid - 11264; }
    int i = (ib * 256 + threadIdx.x) * 4;
    float4 v = *reinterpret_cast<const float4*>(src + i);
    ushort4 o;
    o.x = f2bf(v.x); o.y = f2bf(v.y); o.z = f2bf(v.z); o.w = f2bf(v.w);
    *reinterpret_cast<ushort4*>(dst + i) = o;
}

// ================= 128x256 bf16 GEMM, BK=32, 3-buf counted-vmcnt (B given as [N,K]) ====
// MODE 0 only: q(x0.125*log2e)/k natural [B,H,T,64]; V-blocks (n0>=2048) in-epilogue
// LDS transpose -> vt [B,H,64,T] coalesced (t fast axis).
template<int MODE>
__global__ __launch_bounds__(512, 4) void gemm_bk32(
    const u16* __restrict__ A, const u16* __restrict__ Bw, int M, int N, int K,
    int ntiles_n, const float* __restrict__ bias,
    u16* __restrict__ qo, u16* __restrict__ ko, u16* __restrict__ vo,
    float* __restrict__ out)
{
    __shared__ u16 lds[36864];     // 72 KB
    const int t = threadIdx.x;
    const int lane = t & 63;
    const int wave = t >> 6;
    const int wr = wave >> 2, wc = wave & 3;
    const int lr = lane & 15, lq = lane >> 4;
    const int r3 = lane >> 2, c4 = lane & 3;
    const int cpx = gridDim.x >> 3;
    const int bid = (blockIdx.x & 7) * cpx + (blockIdx.x >> 3);
    const int m0 = (bid / ntiles_n) * 128;
    const int n0 = (bid % ntiles_n) * 256;
    const int NT = K >> 5;

    const u16* AgW  = A  + (size_t)(m0 + wave * 16 + r3) * K + c4 * 8;
    const u16* BgW0 = Bw + (size_t)(n0 + wave * 16 + r3) * K + c4 * 8;
    const u16* BgW1 = BgW0 + (size_t)128 * K;

    auto stage = [&](int buf, int tile) {
        u16* dA  = lds + buf * 12288 + wave * 512;
        u16* dB0 = lds + buf * 12288 + 4096 + wave * 512;
        u16* dB1 = dB0 + 4096;
        __builtin_amdgcn_global_load_lds(
            (const __attribute__((address_space(1))) void*)(AgW + tile * 32),
            (__attribute__((address_space(3))) void*)dA, 16, 0, 0);
        __builtin_amdgcn_global_load_lds(
            (const __attribute__((address_space(1))) void*)(BgW0 + tile * 32),
            (__attribute__((address_space(3))) void*)dB0, 16, 0, 0);
        __builtin_amdgcn_global_load_lds(
            (const __attribute__((address_space(1))) void*)(BgW1 + tile * 32),
            (__attribute__((address_space(3))) void*)dB1, 16, 0, 0);
    };

    f32x4 acc[4][4];
#pragma unroll
    for (int i = 0; i < 4; ++i)
#pragma unroll
        for (int j = 0; j < 4; ++j) acc[i][j] = (f32x4){0.f, 0.f, 0.f, 0.f};

    stage(0, 0);
    stage(1, 1);
    asm volatile("s_waitcnt vmcnt(3)" ::: "memory");
    __builtin_amdgcn_s_barrier();

    for (int T = 0; T < NT; ++T) {
        const int bcur = T % 3;
        const u16* Ab = lds + bcur * 12288;
        const u16* Bb = Ab + 4096;
        bf16x8 a[4], bb[4];
#pragma unroll
        for (int mm = 0; mm < 4; ++mm)
            a[mm] = *reinterpret_cast<const bf16x8*>(Ab + (wr * 64 + mm * 16 + lr) * 32 + lq * 8);
#pragma unroll
        for (int nn = 0; nn < 4; ++nn)
            bb[nn] = *reinterpret_cast<const bf16x8*>(Bb + (wc * 64 + nn * 16 + lr) * 32 + lq * 8);
        if (T + 2 < NT) stage((T + 2) % 3, T + 2);
        __builtin_amdgcn_s_setprio(1);
#pragma unroll
        for (int mm = 0; mm < 4; ++mm)
#pragma unroll
            for (int nn = 0; nn < 4; ++nn)
                acc[mm][nn] = __builtin_amdgcn_mfma_f32_16x16x32_bf16(a[mm], bb[nn], acc[mm][nn], 0, 0, 0);
        __builtin_amdgcn_s_setprio(0);
        if (T + 2 < NT)      asm volatile("s_waitcnt vmcnt(3)" ::: "memory");
        else if (T + 1 < NT) asm volatile("s_waitcnt vmcnt(0)" ::: "memory");
        if (T + 1 < NT) __builtin_amdgcn_s_barrier();
    }

    // ---------------- epilogue (D layout: col=lane&15, row=(lane>>4)*4+reg) ------------
    if (MODE == 0 && n0 >= 2048) {
        __syncthreads();
        u16* patch = lds + wave * 4608;          // [64 col][72 row] u16
#pragma unroll
        for (int m = 0; m < 4; ++m)
#pragma unroll
            for (int n = 0; n < 4; ++n) {
                int c = n * 16 + lr;
                int rrl = m * 16 + lq * 4;
#pragma unroll
                for (int r = 0; r < 4; ++r)
                    patch[c * 72 + rrl + r] = f2bf(acc[m][n][r]);
            }
        const int col0 = n0 + wc * 64;
        const int row0 = m0 + wr * 64;
#pragma unroll
        for (int p = 0; p < 8; ++p) {
            int c = p * 8 + (lane >> 3);
            int tch = (lane & 7) * 8;
            u16x8 v = *reinterpret_cast<const u16x8*>(patch + c * 72 + tch);
            int col = col0 + c;
            int cc = col & 1023;
            int h = cc >> 6, d = cc & 63;
            int rg = row0 + tch;
            int b = rg >> 10, tt = rg & 1023;
            *reinterpret_cast<u16x8*>(vo + (((size_t)(b * 16 + h)) << 16) +
                                      (size_t)d * 1024 + tt) = v;
        }
    } else {
#pragma unroll
        for (int m = 0; m < 4; ++m) {
            int row = m0 + wr * 64 + m * 16 + lq * 4;
#pragma unroll
            for (int n = 0; n < 4; ++n) {
                int col = n0 + wc * 64 + n * 16 + lr;
                float bv = bias[col];
#pragma unroll
                for (int r = 0; r < 4; ++r) {
                    float val = acc[m][n][r] + bv;
                    int rr = row + r;
                    int part = col >> 10;
                    int cc = col & 1023;
                    int h = cc >> 6, d = cc & 63;
                    int b = rr >> 10, tt = rr & 1023;
                    size_t bh = (size_t)(b * 16 + h);
                    u16* dst = (part == 0) ? qo : ko;
                    dst[((bh << 10) + tt) * 64 + d] = f2bf(part == 0 ? val * 0.18033688011f : val);
                }
            }
        }
    }
}

// ===== 128x128 bf16 GEMM, BK=32, 3-buf counted-vmcnt — 4 waves, 2+ blocks/CU ===========
// GEMM2: out = acc + bias + bf2f(fsb). grid = (M/128)*(N/128) = 512 (%8==0).
__global__ __launch_bounds__(256, 4) void gemm_sq128(
    const u16* __restrict__ A, const u16* __restrict__ Bw, int M, int N, int K,
    int ntiles_n, const float* __restrict__ bias,
    const u16* __restrict__ fsb, float* __restrict__ out)
{
    __shared__ u16 lds[24576];     // 48 KB: 3 bufs x (A 4096 + B 4096 u16)
    const int t = threadIdx.x;
    const int lane = t & 63;
    const int wave = t >> 6;                   // 0..3
    const int wr = wave >> 1, wc = wave & 1;   // 2x2 wave grid
    const int lr = lane & 15, lq = lane >> 4;
    const int r3 = lane >> 2, c4 = lane & 3;
    const int cpx = gridDim.x >> 3;
    const int bid = (blockIdx.x & 7) * cpx + (blockIdx.x >> 3);
    const int m0 = (bid / ntiles_n) * 128;
    const int n0 = (bid % ntiles_n) * 128;
    const int NT = K >> 5;

    const u16* AgW = A  + (size_t)(m0 + wave * 16 + r3) * K + c4 * 8;
    const u16* BgW = Bw + (size_t)(n0 + wave * 16 + r3) * K + c4 * 8;

    auto stage = [&](int buf, int tile) {
        u16* dA = lds + buf * 8192 + wave * 512;
        u16* dB = lds + buf * 8192 + 4096 + wave * 512;
        __builtin_amdgcn_global_load_lds(
            (const __attribute__((address_space(1))) void*)(AgW + tile * 32),
            (__attribute__((address_space(3))) void*)dA, 16, 0, 0);
        __builtin_amdgcn_global_load_lds(
            (const __attribute__((address_space(1))) void*)(AgW + (size_t)64 * K + tile * 32),
            (__attribute__((address_space(3))) void*)(dA + 2048), 16, 0, 0);
        __builtin_amdgcn_global_load_lds(
            (const __attribute__((address_space(1))) void*)(BgW + tile * 32),
            (__attribute__((address_space(3))) void*)dB, 16, 0, 0);
        __builtin_amdgcn_global_load_lds(
            (const __attribute__((address_space(1))) void*)(BgW + (size_t)64 * K + tile * 32),
            (__attribute__((address_space(3))) void*)(dB + 2048), 16, 0, 0);
    };

    f32x4 acc[4][4];
#pragma unroll
    for (int i = 0; i < 4; ++i)
#pragma unroll
        for (int j = 0; j < 4; ++j) acc[i][j] = (f32x4){0.f, 0.f, 0.f, 0.f};

    stage(0, 0);
    stage(1, 1);
    asm volatile("s_waitcnt vmcnt(4)" ::: "memory");
    __builtin_amdgcn_s_barrier();

    for (int T = 0; T < NT; ++T) {
        const int bcur = T % 3;
        const u16* Ab = lds + bcur * 8192;
        const u16* Bb = Ab + 4096;
        bf16x8 a[4], bb[4];
#pragma unroll
        for (int mm = 0; mm < 4; ++mm)
            a[mm] = *reinterpret_cast<const bf16x8*>(Ab + (wr * 64 + mm * 16 + lr) * 32 + lq * 8);
#pragma unroll
        for (int nn = 0; nn < 4; ++nn)
            bb[nn] = *reinterpret_cast<const bf16x8*>(Bb + (wc * 64 + nn * 16 + lr) * 32 + lq * 8);
        if (T + 2 < NT) stage((T + 2) % 3, T + 2);
        __builtin_amdgcn_s_setprio(1);
#pragma unroll
        for (int mm = 0; mm < 4; ++mm)
#pragma unroll
            for (int nn = 0; nn < 4; ++nn)
                acc[mm][nn] = __builtin_amdgcn_mfma_f32_16x16x32_bf16(a[mm], bb[nn], acc[mm][nn], 0, 0, 0);
        __builtin_amdgcn_s_setprio(0);
        if (T + 2 < NT)      asm volatile("s_waitcnt vmcnt(4)" ::: "memory");
        else if (T + 1 < NT) asm volatile("s_waitcnt vmcnt(0)" ::: "memory");
        if (T + 1 < NT) __builtin_amdgcn_s_barrier();
    }

    // epilogue: out = acc + bias + fsmn (bf16), write-only d_out
#pragma unroll
    for (int m = 0; m < 4; ++m) {
        int row = m0 + wr * 64 + m * 16 + lq * 4;
#pragma unroll
        for (int n = 0; n < 4; ++n) {
            int col = n0 + wc * 64 + n * 16 + lr;
            float bv = bias[col];
#pragma unroll
            for (int r = 0; r < 4; ++r) {
                size_t o = (size_t)(row + r) * N + col;
                out[o] = acc[m][n][r] + bv + bf2f(fsb[o]);
            }
        }
    }
}

// ========== FAT kernel: blocks <1024 = attn v12; blocks >=1024 = fsmn (bf16 LDS) =======
__global__ __launch_bounds__(256) void attn_fsmn(const u16* __restrict__ qg,
                                                 const u16* __restrict__ kg,
                                                 const u16* __restrict__ vtg,
                                                 const int* __restrict__ mask,
                                                 const float* __restrict__ fk,
                                                 u16* __restrict__ ctx,
                                                 u16* __restrict__ fsb)
{
    __shared__ u16 smem[16384];   // 32 KB overlay
    if (blockIdx.x < 1024) {
        // ---------------- attention v12 body ----------------
        u16* K_sb = smem;          // [2][4096] u16
        u16* V_sb = smem + 8192;   // [2][4096] u16
        const int t = threadIdx.x;
        const int lane = t & 63;
        const int w = t >> 6;                 // 0..3
        const int lr = lane & 15, lq = lane >> 4;
        const int bh = blockIdx.x & 127;
        const int qc = blockIdx.x >> 7;       // 0..7
        const int b = bh >> 4, h = bh & 15;
        const size_t base = (size_t)bh << 16;
        const u16* kb = kg + base;            // [1024 key][64 d]
        const u16* vb = vtg + base;           // [64 d][1024 key]
        const int* mrow = mask + (b << 10);
        const int q0 = qc * 128 + w * 32;

        bf16x8 qf[2][2];
#pragma unroll
        for (int qt = 0; qt < 2; ++qt)
#pragma unroll
            for (int kk = 0; kk < 2; ++kk)
                qf[qt][kk] = *reinterpret_cast<const bf16x8*>(
                    qg + base + (size_t)(q0 + qt * 16 + lr) * 64 + kk * 32 + lq * 8);

        f32x4 oacc[2][4];
        f32x4 oacc_l[2];
#pragma unroll
        for (int qt = 0; qt < 2; ++qt) {
            oacc_l[qt] = (f32x4){0.f, 0.f, 0.f, 0.f};
#pragma unroll
            for (int dt = 0; dt < 4; ++dt) oacc[qt][dt] = (f32x4){0.f, 0.f, 0.f, 0.f};
        }

        s16x4 ones_f;
#pragma unroll
        for (int j = 0; j < 4; ++j) ones_f[j] = (short)0x3F80;

        auto stage = [&](int bufi, int tile) {
            const int k0s = tile * 64;
#pragma unroll
            for (int rd = 0; rd < 2; ++rd) {
                int ch = rd * 256 + w * 64 + lane;
                int row = ch >> 3, c7 = ch & 7;
                int sc = (c7 ^ (row & 7)) * 8;
                const u16* srcK = kb + (size_t)(k0s + row) * 64 + sc;
                const u16* srcV = vb + (size_t)row * 1024 + k0s + sc;
                u16* dK = K_sb + bufi * 4096 + (size_t)(rd * 256 + w * 64) * 8;
                u16* dV = V_sb + bufi * 4096 + (size_t)(rd * 256 + w * 64) * 8;
                __builtin_amdgcn_global_load_lds(
                    (const __attribute__((address_space(1))) void*)srcK,
                    (__attribute__((address_space(3))) void*)dK, 16, 0, 0);
                __builtin_amdgcn_global_load_lds(
                    (const __attribute__((address_space(1))) void*)srcV,
                    (__attribute__((address_space(3))) void*)dV, 16, 0, 0);
            }
        };

        stage(0, 0);
        asm volatile("s_waitcnt vmcnt(0)");
        __syncthreads();

        for (int it = 0; it < 16; ++it) {
            const u16* Kb = K_sb + (it & 1) * 4096;
            const u16* Vb = V_sb + (it & 1) * 4096;
            if (it < 15) stage((it + 1) & 1, it + 1);

            bf16x8 kf[4][2];
#pragma unroll
            for (int kt = 0; kt < 4; ++kt) {
                int row = kt * 16 + lr;
#pragma unroll
                for (int kk = 0; kk < 2; ++kk) {
                    int g = (kk * 4 + lq) ^ (row & 7);
                    kf[kt][kk] = *reinterpret_cast<const bf16x8*>(Kb + row * 64 + g * 8);
                }
            }

            int mv = mrow[it * 64 + lane];
            unsigned long long bal = __ballot(mv != 0);
            uint32_t mw0 = (uint32_t)bal, mw1 = (uint32_t)(bal >> 32);
            uint32_t mb_[4];
            mb_[0] = mw0 >> (lq * 4);
            mb_[1] = mw0 >> (16 + lq * 4);
            mb_[2] = mw1 >> (lq * 4);
            mb_[3] = mw1 >> (16 + lq * 4);
            f32x4 ma[4];
#pragma unroll
            for (int kt = 0; kt < 4; ++kt)
#pragma unroll
                for (int r = 0; r < 4; ++r)
                    ma[kt][r] = (mb_[kt] & (1u << r)) ? 0.f : -3e38f;

            s16x4 vf[4][4];
#pragma unroll
            for (int ks = 0; ks < 4; ++ks)
#pragma unroll
                for (int dt = 0; dt < 4; ++dt) {
                    int row = dt * 16 + lr;
                    int g = (ks * 2 + (lq >> 1)) ^ (row & 7);
                    vf[ks][dt] = *reinterpret_cast<const s16x4*>(Vb + row * 64 + g * 8 + (lq & 1) * 4);
                }

#pragma unroll
            for (int qt = 0; qt < 2; ++qt) {
                f32x4 s[4];
                __builtin_amdgcn_s_setprio(1);
#pragma unroll
                for (int kt = 0; kt < 4; ++kt) {
                    s[kt] = __builtin_amdgcn_mfma_f32_16x16x32_bf16(kf[kt][0], qf[qt][0], ma[kt], 0, 0, 0);
                    s[kt] = __builtin_amdgcn_mfma_f32_16x16x32_bf16(kf[kt][1], qf[qt][1], s[kt], 0, 0, 0);
                }
                __builtin_amdgcn_s_setprio(0);

                union { uint32_t u[2]; s16x4 v; } pa[4];
#pragma unroll
                for (int kt = 0; kt < 4; ++kt) {
                    float p0 = __builtin_amdgcn_exp2f(s[kt][0]);
                    float p1 = __builtin_amdgcn_exp2f(s[kt][1]);
                    float p2 = __builtin_amdgcn_exp2f(s[kt][2]);
                    float p3 = __builtin_amdgcn_exp2f(s[kt][3]);
                    pa[kt].u[0] = pack_bf16(p0, p1);
                    pa[kt].u[1] = pack_bf16(p2, p3);
                }

                __builtin_amdgcn_s_setprio(1);
#pragma unroll
                for (int dt = 0; dt < 4; ++dt) {
                    f32x4 o = oacc[qt][dt];
#pragma unroll
                    for (int kt = 0; kt < 4; ++kt)
                        o = __builtin_amdgcn_mfma_f32_16x16x16bf16_1k(vf[kt][dt], pa[kt].v, o, 0, 0, 0);
                    oacc[qt][dt] = o;
                }
#pragma unroll
                for (int kt = 0; kt < 4; ++kt)
                    oacc_l[qt] = __builtin_amdgcn_mfma_f32_16x16x16bf16_1k(ones_f, pa[kt].v, oacc_l[qt], 0, 0, 0);
                __builtin_amdgcn_s_setprio(0);
            }

            if (it < 15) {
                asm volatile("s_waitcnt vmcnt(0)" ::: "memory");
                __syncthreads();
            }
        }

#pragma unroll
        for (int qt = 0; qt < 2; ++qt) {
            float li = 1.f / oacc_l[qt][0];
            int trow = q0 + qt * 16 + lr;
            u16* crow = ctx + ((size_t)(b << 10) + trow) * 1024 + h * 64;
#pragma unroll
            for (int dt = 0; dt < 4; ++dt) {
                f32x4 o = oacc[qt][dt];
                u16x4 pkv;
                pkv[0] = f2bf(o[0] * li); pkv[1] = f2bf(o[1] * li);
                pkv[2] = f2bf(o[2] * li); pkv[3] = f2bf(o[3] * li);
                *reinterpret_cast<u16x4*>(crow + dt * 16 + lq * 4) = pkv;
            }
        }
    } else {
        // ---------------- FSMN body (bf16 LDS overlay, 19.4 KB) ----------------
        u16* vsu = smem;                                 // [64][147] u16 (premasked V)
        float* ms = (float*)(smem + 9408);               // [144] f32
        const int fb = blockIdx.x - 1024;
        const int tid = threadIdx.x;
        const int tc = fb & 7;
        const int bh = fb >> 3;
        const int b = bh >> 4, h = bh & 15;
        const int t0 = tc * 128;
        const u16* vrow = vtg + ((size_t)bh << 16);
        const int* mrow = mask + (b << 10);

        if (tid < 144) {
            int tt = t0 - 8 + tid;
            ms[tid] = (tt >= 0 && tt < 1024) ? (float)mrow[tt] : 0.f;
        }
        const int sd = tid >> 2;
        const int ci0 = tid & 3;
#pragma unroll
        for (int it = 0; it < 5; ++it) {
            int ci = ci0 + it * 4;
            if (ci < 18) {
                int tbase = t0 - 8 + ci * 8;
                if (tbase >= 0 && tbase < 1024) {
                    u16x8 v8 = *reinterpret_cast<const u16x8*>(vrow + (size_t)sd * 1024 + tbase);
#pragma unroll
                    for (int j = 0; j < 8; ++j)
                        vsu[sd * 147 + ci * 8 + j] = mrow[tbase + j] ? (u16)v8[j] : (u16)0;
                } else {
#pragma unroll
                    for (int j = 0; j < 8; ++j) vsu[sd * 147 + ci * 8 + j] = 0;
                }
            }
        }
        __syncthreads();

        const int dd = tid & 63;
        const int tg = tid >> 6;
        const int c = h * 64 + dd;
        float kc[11];
#pragma unroll
        for (int j = 0; j < 11; ++j) kc[j] = fk[c * 11 + j];

        const int tl0 = tg * 32;
        float w[11];
#pragma unroll
        for (int j = 0; j < 11; ++j) w[j] = bf2f(vsu[dd * 147 + 3 + tl0 + j]);
        u16* orow = fsb + ((size_t)(b * 1024 + t0 + tl0)) * 1024 + c;
#pragma unroll 4
        for (int s = 0; s < 32; ++s) {
            float acc = 0.f;
#pragma unroll
            for (int j = 0; j < 11; ++j) acc += kc[j] * w[j];
            float mf = ms[8 + tl0 + s];
            orow[(size_t)s * 1024] = f2bf((acc + w[5]) * mf);
#pragma unroll
            for (int j = 0; j < 10; ++j) w[j] = w[j + 1];
            w[10] = bf2f(vsu[dd * 147 + 3 + tl0 + s + 11]);
        }
    }
}

extern "C" void kernel_launch(void* const* d_in, const int* in_sizes, int n_in,
                              void* d_out, int out_size, void* d_ws, size_t ws_size,
                              hipStream_t stream)
{
    (void)in_sizes; (void)n_in; (void)out_size; (void)ws_size;
    const float* hs   = (const float*)d_in[0];
    const int*   mask = (const int*)d_in[1];
    const float* Wqkv = (const float*)d_in[2];
    const float* bqkv = (const float*)d_in[3];
    const float* Wout = (const float*)d_in[4];
    const float* bout = (const float*)d_in[5];
    const float* fk   = (const float*)d_in[6];
    float* out = (float*)d_out;

    char* ws = (char*)d_ws;
    u16* hsb   = (u16*)(ws);
    u16* wqkvb = (u16*)(ws + 16777216);
    u16* woutb = (u16*)(ws + 23068672);
    u16* qb    = (u16*)(ws + 25165824);      // [B,H,T,64]
    u16* kb    = (u16*)(ws + 41943040);      // [B,H,T,64]
    u16* vtb   = (u16*)(ws + 58720256);      // [B,H,64,T]
    u16* ctxb  = (u16*)(ws + 75497472);      // [B,T,1024]
    u16* fsb   = (u16*)(ws + 65536);         // 16MB bf16 fsmn memory (hsb+wqkvb region,
                                             //  written AFTER gemm1)

    cvt_all<<<12288, 256, 0, stream>>>(hs, Wqkv, Wout, hsb, wqkvb, woutb);

    gemm_bk32<0><<<64 * 12, 512, 0, stream>>>(hsb, wqkvb, 8192, 3072, 1024, 12,
                                              bqkv, qb, kb, vtb, nullptr);
    attn_fsmn<<<2048, 256, 0, stream>>>(qb, kb, vtb, mask, fk, ctxb, fsb);
    gemm_sq128<<<64 * 8, 256, 0, stream>>>(ctxb, woutb, 8192, 1024, 1024, 8,
                                           bout, fsb, out);
}